// Round 14
// baseline (195.918 us; speedup 1.0000x reference)
//
#include <hip/hip_runtime.h>
#include <hip/hip_bf16.h>

// Problem constants
#define B_    32
#define T_    512
#define C_    384
#define D_    1536      // C*MULT
#define H_    1024
#define L_    255       // (T-SIZE)/STRIDE + 1
#define KP_   6144      // SIZE*D
#define ND_   16

// gemm1 (bf16, r3 engine): unchanged from r13.
// gemm2 (MX-fp8 K=128): BM=128(l) BN=128(h), 4 waves, wave tile 64x64,
//   2 blocks/CU. A (X18) loaded GLOBAL->REG directly (lane-row-contiguous
//   MFMA fragment; L1/L2 resident), prefetched 1 tile ahead. LDS holds only
//   B: 2 x 16KB double buffer. vmcnt(12) counted (= B(u+1) 4 + A(u+1) 8).
#define BUFB 49152

using f32x4 = __attribute__((ext_vector_type(4))) float;
using s16x8 = __attribute__((ext_vector_type(8))) short;
using i32x4 = __attribute__((ext_vector_type(4))) int;
using i32x8 = __attribute__((ext_vector_type(8))) int;

__device__ __forceinline__ void gld_lds16(const void* g, void* l) {
    __builtin_amdgcn_global_load_lds(
        (const __attribute__((address_space(1))) void*)g,
        (__attribute__((address_space(3))) void*)l,
        16, 0, 0);
}

__device__ __forceinline__ f32x4 MFMA(s16x8 a, s16x8 b, f32x4 c) {
    return __builtin_amdgcn_mfma_f32_16x16x32_bf16(a, b, c, 0, 0, 0);
}

// MX-fp8 K=128: A scale 1.0 (e8m0 0x7F), B scale 2^-4 (0x7B; Wp pre-scaled x16)
__device__ __forceinline__ f32x4 MFMA8(i32x8 a, i32x8 b, f32x4 c) {
    return __builtin_amdgcn_mfma_scale_f32_16x16x128_f8f6f4(
        a, b, c, 0, 0, 0, 0x7F7F7F7F, 0, 0x7B7B7B7B);
}

// ------------- prep: conversions + mask/ts, one launch ------------------
__global__ __launch_bounds__(256) void prep(
    const float* __restrict__ sp, const float* __restrict__ we,
    const float* __restrict__ wp, const int* __restrict__ mIn,
    const int* __restrict__ tIn,
    __hip_bfloat16* __restrict__ spB, __hip_bfloat16* __restrict__ weB,
    unsigned char* __restrict__ wp8, float* __restrict__ out) {
    int id = blockIdx.x * 256 + threadIdx.x;
    if (id < 3932160) {
        const float* src; __hip_bfloat16* dst; int idx;
        if (id < 1572864) { src = sp; dst = spB; idx = id; }
        else              { src = we; dst = weB; idx = id - 1572864; }
        float4 v = reinterpret_cast<const float4*>(src)[idx];
        __hip_bfloat16 o[4] = {__float2bfloat16(v.x), __float2bfloat16(v.y),
                               __float2bfloat16(v.z), __float2bfloat16(v.w)};
        reinterpret_cast<ushort4*>(dst)[idx] = *reinterpret_cast<ushort4*>(o);
    } else if (id < 5505024) {
        int idx = id - 3932160;
        float4 v = reinterpret_cast<const float4*>(wp)[idx];
        int w = __builtin_amdgcn_cvt_pk_fp8_f32(v.x * 16.f, v.y * 16.f, 0, false);
        w = __builtin_amdgcn_cvt_pk_fp8_f32(v.z * 16.f, v.w * 16.f, w, true);
        reinterpret_cast<int*>(wp8)[idx] = w;
    } else {
        int i = id - 5505024;
        if (i < B_ * L_) {
            int b = i / L_, l = i % L_;
            const int* mb = mIn + b * T_ + 2 * l;
            int m = mb[0] * mb[1] * mb[2] * mb[3];
            const size_t offM = (size_t)B_ * L_ * H_;
            out[offM + i] = (float)m;
            out[offM + (size_t)B_ * L_ + i] = (float)tIn[b * T_ + l];
        }
    }
}

// ======================= gemm1 engine (r3/r9, bf16) ======================
__device__ __forceinline__ void tile_compute(const char* la, const char* lb,
                                             f32x4 (&acc)[4][4],
                                             int rA, int rB, int g) {
    const int sxA = rA & 7, sxB = rB & 7;
    s16x8 af0[4], bf0[4], af1[4], bf1[4];
    #pragma unroll
    for (int mi = 0; mi < 4; ++mi)
        af0[mi] = *(const s16x8*)(la + rA * 128 + mi * 2048 + ((g ^ sxA) << 4));
    #pragma unroll
    for (int ni = 0; ni < 4; ++ni)
        bf0[ni] = *(const s16x8*)(lb + rB * 128 + ni * 2048 + ((g ^ sxB) << 4));
    #pragma unroll
    for (int mi = 0; mi < 4; ++mi)
        af1[mi] = *(const s16x8*)(la + rA * 128 + mi * 2048 + (((4 + g) ^ sxA) << 4));
    #pragma unroll
    for (int ni = 0; ni < 4; ++ni)
        bf1[ni] = *(const s16x8*)(lb + rB * 128 + ni * 2048 + (((4 + g) ^ sxB) << 4));
    asm volatile("s_waitcnt lgkmcnt(8)" ::: "memory");
    __builtin_amdgcn_sched_barrier(0);
    __builtin_amdgcn_s_setprio(1);
    #pragma unroll
    for (int mi = 0; mi < 4; ++mi)
        #pragma unroll
        for (int ni = 0; ni < 4; ++ni)
            acc[mi][ni] = MFMA(af0[mi], bf0[ni], acc[mi][ni]);
    __builtin_amdgcn_s_setprio(0);
    asm volatile("s_waitcnt lgkmcnt(0)" ::: "memory");
    __builtin_amdgcn_sched_barrier(0);
    __builtin_amdgcn_s_setprio(1);
    #pragma unroll
    for (int mi = 0; mi < 4; ++mi)
        #pragma unroll
        for (int ni = 0; ni < 4; ++ni)
            acc[mi][ni] = MFMA(af1[mi], bf1[ni], acc[mi][ni]);
    __builtin_amdgcn_s_setprio(0);
}

__global__ __launch_bounds__(512, 2) void gemm1_embed(
    const __hip_bfloat16* __restrict__ Sp,
    const __hip_bfloat16* __restrict__ We,
    const float* __restrict__ bEmb,
    const int* __restrict__ dateIdx,
    unsigned char* __restrict__ X18) {
    extern __shared__ __align__(16) char lds[];
    const int tid  = threadIdx.x;
    const int lane = tid & 63, wid = tid >> 6;
    const int wr = wid >> 1, wc = wid & 1;
    const int id   = blockIdx.x;             // 0..767
    const int xcd  = id & 7, slot = id >> 3; // slot 0..95
    const int b    = xcd * 4 + slot / 24;
    const int tile = slot % 24;
    const int m0   = (tile % 2) * 256;
    const int n0   = (tile / 2) * 128;
    const int didx = dateIdx[b];
    const __hip_bfloat16* A  = Sp + (size_t)b * T_ * C_;
    const __hip_bfloat16* Bm = We + (size_t)didx * D_ * C_;
    const int KT = C_ / 64;              // 6

    auto stage = [&](int kt, int buf) {
        char* lA = lds + buf * BUFB;
        char* lB = lA + 32768;
        int k0 = kt * 64;
        #pragma unroll
        for (int i = 0; i < 4; ++i) {
            int p = i * 512 + tid;
            int row = p >> 3;
            int clog = (p & 7) ^ (row & 7);
            gld_lds16(A + (size_t)(m0 + row) * C_ + k0 + clog * 8,
                      lA + (i * 512 + wid * 64) * 16);
        }
        #pragma unroll
        for (int i = 0; i < 2; ++i) {
            int p = i * 512 + tid;
            int row = p >> 3;
            int clog = (p & 7) ^ (row & 7);
            gld_lds16(Bm + (size_t)(n0 + row) * C_ + k0 + clog * 8,
                      lB + (i * 512 + wid * 64) * 16);
        }
    };

    f32x4 acc[4][4] = {};
    const int rl = lane & 15, g = lane >> 4;
    const int rA = wr * 64 + rl, rB = wc * 64 + rl;

    stage(0, 0);
    stage(1, 1);
    for (int kt = 0; kt < KT - 2; ++kt) {
        stage(kt + 2, (kt + 2) % 3);
        asm volatile("s_waitcnt vmcnt(12)" ::: "memory");
        __builtin_amdgcn_s_barrier();
        const char* la = lds + (kt % 3) * BUFB;
        tile_compute(la, la + 32768, acc, rA, rB, g);
        __builtin_amdgcn_s_barrier();
    }
    asm volatile("s_waitcnt vmcnt(6)" ::: "memory");
    __builtin_amdgcn_s_barrier();
    {
        const char* la = lds + ((KT - 2) % 3) * BUFB;
        tile_compute(la, la + 32768, acc, rA, rB, g);
    }
    asm volatile("s_waitcnt vmcnt(0)" ::: "memory");
    __builtin_amdgcn_s_barrier();
    {
        const char* la = lds + ((KT - 1) % 3) * BUFB;
        tile_compute(la, la + 32768, acc, rA, rB, g);
    }

    // epilogue: + bias, exact gelu, * 32, store fp8 e4m3
    #pragma unroll
    for (int mi = 0; mi < 4; ++mi) {
        #pragma unroll
        for (int ni = 0; ni < 4; ++ni) {
            int col = n0 + wc * 64 + ni * 16 + rl;              // d
            float bg = bEmb[didx * D_ + col];
            #pragma unroll
            for (int r = 0; r < 4; ++r) {
                int row = m0 + wr * 64 + mi * 16 + g * 4 + r;   // t
                float v = acc[mi][ni][r] + bg;
                float gl = 0.5f * v * (1.0f + erff(v * 0.70710678118f)) * 32.0f;
                int pk = __builtin_amdgcn_cvt_pk_fp8_f32(gl, gl, 0, false);
                X18[((size_t)b * T_ + row) * D_ + col] = (unsigned char)pk;
            }
        }
    }
}

// ===== gemm2: MX-fp8 K128, A global->reg prefetch, B-only LDS ============
// grid 512: xcd=id&7; slot=id>>3; b=xcd*4+(slot>>4); t=slot&15:
// m0=(t&1)*128, n0=(t>>1)*128. 48 K128-tiles, s-inner order. 2 blocks/CU.
__global__ __launch_bounds__(256, 2) void gemm2_proj(
    const unsigned char* __restrict__ X18,     // [B][T][D] fp8
    const unsigned char* __restrict__ Wp8,     // [H][KP] fp8 (x16 scaled)
    const float* __restrict__ bProj,
    const float* __restrict__ posTab,          // [MAXF][H] f32
    const int* __restrict__ tsIn,              // [B][T]
    float* __restrict__ outX) {                // [B][L][H]
    __shared__ __align__(16) char ldsB[2][16384];
    const int tid  = threadIdx.x;
    const int lane = tid & 63, wid = tid >> 6;
    const int wm = wid >> 1, wn = wid & 1;
    const int id   = blockIdx.x;               // 0..511
    const int xcd  = id & 7, slot = id >> 3;   // 0..63
    const int b    = xcd * 4 + (slot >> 4);
    const int t    = slot & 15;
    const int m0   = (t & 1) * 128;            // l base
    const int n0   = (t >> 1) * 128;           // h base
    const unsigned char* Xb = X18 + (size_t)b * T_ * D_;
    const int KT = 48;                         // K128 tiles

    // ---- B staging (gload_lds, swizzled): 4 x 16B per thread per tile
    const unsigned char* bP[4]; int dstC[4];
    #pragma unroll
    for (int i = 0; i < 4; ++i) {
        int p = i * 256 + tid;
        int row = p >> 3;
        int c = (p & 7) ^ (row & 7);
        bP[i] = Wp8 + (size_t)(n0 + row) * KP_ + c * 16;
        dstC[i] = (i * 256 + wid * 64) * 16;
    }
    auto kofs = [&](int kt) { return (kt & 3) * D_ + (kt >> 2) * 128; };
    auto stageB = [&](int kt, int buf) {
        int ko = kofs(kt);
        #pragma unroll
        for (int i = 0; i < 4; ++i)
            gld_lds16(bP[i] + ko, &ldsB[buf][dstC[i]]);
    };

    // ---- A fragment global addresses (lane-row-contiguous, 32B per frag)
    const int rl = lane & 15, g = lane >> 4, sx = rl & 7;
    const unsigned char* aAddr[4];
    #pragma unroll
    for (int mi = 0; mi < 4; ++mi) {
        int l = m0 + wm * 64 + mi * 16 + rl; if (l > 254) l = 254;
        aAddr[mi] = Xb + (size_t)(2 * l) * D_ + g * 32;
    }
    auto loadA = [&](i32x8 (&dst)[4], int kt) {
        int ko = kofs(kt);
        #pragma unroll
        for (int mi = 0; mi < 4; ++mi) {
            i32x4 lo = *(const i32x4*)(aAddr[mi] + ko);
            i32x4 hi = *(const i32x4*)(aAddr[mi] + ko + 16);
            dst[mi] = __builtin_shufflevector(lo, hi, 0, 1, 2, 3, 4, 5, 6, 7);
        }
    };

    // ---- B fragment LDS geometry (2 x b128 per frag, XOR swizzled)
    const int ck0 = ((2 * g) ^ sx) << 4;
    const int ck1 = ((2 * g + 1) ^ sx) << 4;
    int bOff[4];
    #pragma unroll
    for (int ni = 0; ni < 4; ++ni) bOff[ni] = (wn * 64 + ni * 16 + rl) * 128;

    union u8x32 { i32x8 v; i32x4 h[2]; };
    f32x4 acc[4][4] = {};
    i32x8 Acur[4], Anxt[4];

    stageB(0, 0);
    loadA(Acur, 0);
    for (int u = 0; u < KT; ++u) {
        int buf = u & 1;
        if (u + 1 < KT) {
            stageB(u + 1, buf ^ 1);      // 4 gld_lds
            loadA(Anxt, u + 1);          // 8 global loads
            asm volatile("s_waitcnt vmcnt(12)" ::: "memory");  // B(u)+A(u) done
        } else {
            asm volatile("s_waitcnt vmcnt(0)" ::: "memory");
        }
        __builtin_amdgcn_s_barrier();

        u8x32 Bv[4];
        #pragma unroll
        for (int ni = 0; ni < 4; ++ni) {
            Bv[ni].h[0] = *(const i32x4*)(&ldsB[buf][0] + bOff[ni] + ck0);
            Bv[ni].h[1] = *(const i32x4*)(&ldsB[buf][0] + bOff[ni] + ck1);
        }
        #pragma unroll
        for (int ni = 0; ni < 4; ++ni)
            #pragma unroll
            for (int mi = 0; mi < 4; ++mi)
                acc[mi][ni] = MFMA8(Acur[mi], Bv[ni].v, acc[mi][ni]);
        __builtin_amdgcn_s_barrier();    // all B reads of buf done

        #pragma unroll
        for (int mi = 0; mi < 4; ++mi) Acur[mi] = Anxt[mi];
    }

    // epilogue: + b_proj + pos_table[ts[l]], fp32 store
    #pragma unroll
    for (int mi = 0; mi < 4; ++mi) {
        #pragma unroll
        for (int ni = 0; ni < 4; ++ni) {
            int h = n0 + wn * 64 + ni * 16 + rl;
            float bp = bProj[h];
            #pragma unroll
            for (int r = 0; r < 4; ++r) {
                int l = m0 + wm * 64 + mi * 16 + g * 4 + r;
                if (l < L_) {
                    int tsv = tsIn[b * T_ + l];
                    float v = acc[mi][ni][r] + bp + posTab[(size_t)tsv * H_ + h];
                    outX[((size_t)b * L_ + l) * H_ + h] = v;
                }
            }
        }
    }
}

extern "C" void kernel_launch(void* const* d_in, const int* in_sizes, int n_in,
                              void* d_out, int out_size, void* d_ws, size_t ws_size,
                              hipStream_t stream) {
    (void)in_sizes; (void)n_in; (void)out_size; (void)ws_size;
    const float* spikes  = (const float*)d_in[0];
    const int*   smask   = (const int*)d_in[1];
    const int*   sts     = (const int*)d_in[2];
    const int*   dateIdx = (const int*)d_in[3];
    const float* Wemb    = (const float*)d_in[4];
    const float* bEmb    = (const float*)d_in[5];
    const float* Wproj   = (const float*)d_in[6];
    const float* bProj   = (const float*)d_in[7];
    const float* posTab  = (const float*)d_in[8];
    float* out = (float*)d_out;

    // workspace layout (bytes):
    // X18 fp8   [B][T][D]  : 25165824   @ 0
    // SpB bf16  [B][T][C]  : 12582912   @ 25165824
    // WeB bf16  [ND][D][C] : 18874368   @ 37748736
    // Wp8 fp8   [H][KP]    : 6291456    @ 56623104
    char* ws = (char*)d_ws;
    unsigned char*  X18 = (unsigned char*)(ws);
    __hip_bfloat16* SpB = (__hip_bfloat16*)(ws + 25165824);
    __hip_bfloat16* WeB = (__hip_bfloat16*)(ws + 37748736);
    unsigned char*  Wp8 = (unsigned char*)(ws + 56623104);

    hipFuncSetAttribute((const void*)gemm1_embed,
                        hipFuncAttributeMaxDynamicSharedMemorySize, 3 * BUFB);

    prep<<<21536, 256, 0, stream>>>(spikes, Wemb, Wproj, smask, sts,
                                    SpB, WeB, Wp8, out);

    gemm1_embed<<<768, 512, 3 * BUFB, stream>>>(SpB, WeB, bEmb, dateIdx, X18);

    gemm2_proj<<<512, 256, 0, stream>>>(X18, Wp8, bProj, posTab, sts, out);
}

// Round 15
// 124.040 us; speedup vs baseline: 1.5795x; 1.5795x over previous
//
#include <hip/hip_runtime.h>
#include <hip/hip_bf16.h>

// Problem constants
#define B_    32
#define T_    512
#define C_    384
#define D_    1536      // C*MULT
#define H_    1024
#define L_    255       // (T-SIZE)/STRIDE + 1
#define KP_   6144      // SIZE*D
#define ND_   16

// gemm1 (bf16, r3 engine): unchanged from r13 (133.6us run).
// gemm2 (MX-fp8 K=128): BM=128(l) BN=128(h), now 512 threads = 8 waves
//   (2M x 4N, wave tile 64x32) -> 16 waves/CU at 2 blocks/CU (was 8).
//   Same r13 staging/swizzle/counted-vmcnt ring; LDS 2 x 32KB dynamic.
#define BUFB 49152

using f32x4 = __attribute__((ext_vector_type(4))) float;
using s16x8 = __attribute__((ext_vector_type(8))) short;
using i32x4 = __attribute__((ext_vector_type(4))) int;
using i32x8 = __attribute__((ext_vector_type(8))) int;

__device__ __forceinline__ void gld_lds16(const void* g, void* l) {
    __builtin_amdgcn_global_load_lds(
        (const __attribute__((address_space(1))) void*)g,
        (__attribute__((address_space(3))) void*)l,
        16, 0, 0);
}

__device__ __forceinline__ f32x4 MFMA(s16x8 a, s16x8 b, f32x4 c) {
    return __builtin_amdgcn_mfma_f32_16x16x32_bf16(a, b, c, 0, 0, 0);
}

// MX-fp8 K=128: A scale 1.0 (e8m0 0x7F), B scale 2^-4 (0x7B; Wp pre-scaled x16)
__device__ __forceinline__ f32x4 MFMA8(i32x8 a, i32x8 b, f32x4 c) {
    return __builtin_amdgcn_mfma_scale_f32_16x16x128_f8f6f4(
        a, b, c, 0, 0, 0, 0x7F7F7F7F, 0, 0x7B7B7B7B);
}

// ------------- prep: conversions + mask/ts, one launch ------------------
__global__ __launch_bounds__(256) void prep(
    const float* __restrict__ sp, const float* __restrict__ we,
    const float* __restrict__ wp, const int* __restrict__ mIn,
    const int* __restrict__ tIn,
    __hip_bfloat16* __restrict__ spB, __hip_bfloat16* __restrict__ weB,
    unsigned char* __restrict__ wp8, float* __restrict__ out) {
    int id = blockIdx.x * 256 + threadIdx.x;
    if (id < 3932160) {
        const float* src; __hip_bfloat16* dst; int idx;
        if (id < 1572864) { src = sp; dst = spB; idx = id; }
        else              { src = we; dst = weB; idx = id - 1572864; }
        float4 v = reinterpret_cast<const float4*>(src)[idx];
        __hip_bfloat16 o[4] = {__float2bfloat16(v.x), __float2bfloat16(v.y),
                               __float2bfloat16(v.z), __float2bfloat16(v.w)};
        reinterpret_cast<ushort4*>(dst)[idx] = *reinterpret_cast<ushort4*>(o);
    } else if (id < 5505024) {
        int idx = id - 3932160;
        float4 v = reinterpret_cast<const float4*>(wp)[idx];
        int w = __builtin_amdgcn_cvt_pk_fp8_f32(v.x * 16.f, v.y * 16.f, 0, false);
        w = __builtin_amdgcn_cvt_pk_fp8_f32(v.z * 16.f, v.w * 16.f, w, true);
        reinterpret_cast<int*>(wp8)[idx] = w;
    } else {
        int i = id - 5505024;
        if (i < B_ * L_) {
            int b = i / L_, l = i % L_;
            const int* mb = mIn + b * T_ + 2 * l;
            int m = mb[0] * mb[1] * mb[2] * mb[3];
            const size_t offM = (size_t)B_ * L_ * H_;
            out[offM + i] = (float)m;
            out[offM + (size_t)B_ * L_ + i] = (float)tIn[b * T_ + l];
        }
    }
}

// ======================= gemm1 engine (r3/r9, bf16) ======================
__device__ __forceinline__ void tile_compute(const char* la, const char* lb,
                                             f32x4 (&acc)[4][4],
                                             int rA, int rB, int g) {
    const int sxA = rA & 7, sxB = rB & 7;
    s16x8 af0[4], bf0[4], af1[4], bf1[4];
    #pragma unroll
    for (int mi = 0; mi < 4; ++mi)
        af0[mi] = *(const s16x8*)(la + rA * 128 + mi * 2048 + ((g ^ sxA) << 4));
    #pragma unroll
    for (int ni = 0; ni < 4; ++ni)
        bf0[ni] = *(const s16x8*)(lb + rB * 128 + ni * 2048 + ((g ^ sxB) << 4));
    #pragma unroll
    for (int mi = 0; mi < 4; ++mi)
        af1[mi] = *(const s16x8*)(la + rA * 128 + mi * 2048 + (((4 + g) ^ sxA) << 4));
    #pragma unroll
    for (int ni = 0; ni < 4; ++ni)
        bf1[ni] = *(const s16x8*)(lb + rB * 128 + ni * 2048 + (((4 + g) ^ sxB) << 4));
    asm volatile("s_waitcnt lgkmcnt(8)" ::: "memory");
    __builtin_amdgcn_sched_barrier(0);
    __builtin_amdgcn_s_setprio(1);
    #pragma unroll
    for (int mi = 0; mi < 4; ++mi)
        #pragma unroll
        for (int ni = 0; ni < 4; ++ni)
            acc[mi][ni] = MFMA(af0[mi], bf0[ni], acc[mi][ni]);
    __builtin_amdgcn_s_setprio(0);
    asm volatile("s_waitcnt lgkmcnt(0)" ::: "memory");
    __builtin_amdgcn_sched_barrier(0);
    __builtin_amdgcn_s_setprio(1);
    #pragma unroll
    for (int mi = 0; mi < 4; ++mi)
        #pragma unroll
        for (int ni = 0; ni < 4; ++ni)
            acc[mi][ni] = MFMA(af1[mi], bf1[ni], acc[mi][ni]);
    __builtin_amdgcn_s_setprio(0);
}

__global__ __launch_bounds__(512, 2) void gemm1_embed(
    const __hip_bfloat16* __restrict__ Sp,
    const __hip_bfloat16* __restrict__ We,
    const float* __restrict__ bEmb,
    const int* __restrict__ dateIdx,
    unsigned char* __restrict__ X18) {
    extern __shared__ __align__(16) char lds[];
    const int tid  = threadIdx.x;
    const int lane = tid & 63, wid = tid >> 6;
    const int wr = wid >> 1, wc = wid & 1;
    const int id   = blockIdx.x;             // 0..767
    const int xcd  = id & 7, slot = id >> 3; // slot 0..95
    const int b    = xcd * 4 + slot / 24;
    const int tile = slot % 24;
    const int m0   = (tile % 2) * 256;
    const int n0   = (tile / 2) * 128;
    const int didx = dateIdx[b];
    const __hip_bfloat16* A  = Sp + (size_t)b * T_ * C_;
    const __hip_bfloat16* Bm = We + (size_t)didx * D_ * C_;
    const int KT = C_ / 64;              // 6

    auto stage = [&](int kt, int buf) {
        char* lA = lds + buf * BUFB;
        char* lB = lA + 32768;
        int k0 = kt * 64;
        #pragma unroll
        for (int i = 0; i < 4; ++i) {
            int p = i * 512 + tid;
            int row = p >> 3;
            int clog = (p & 7) ^ (row & 7);
            gld_lds16(A + (size_t)(m0 + row) * C_ + k0 + clog * 8,
                      lA + (i * 512 + wid * 64) * 16);
        }
        #pragma unroll
        for (int i = 0; i < 2; ++i) {
            int p = i * 512 + tid;
            int row = p >> 3;
            int clog = (p & 7) ^ (row & 7);
            gld_lds16(Bm + (size_t)(n0 + row) * C_ + k0 + clog * 8,
                      lB + (i * 512 + wid * 64) * 16);
        }
    };

    f32x4 acc[4][4] = {};
    const int rl = lane & 15, g = lane >> 4;
    const int rA = wr * 64 + rl, rB = wc * 64 + rl;

    stage(0, 0);
    stage(1, 1);
    for (int kt = 0; kt < KT - 2; ++kt) {
        stage(kt + 2, (kt + 2) % 3);
        asm volatile("s_waitcnt vmcnt(12)" ::: "memory");
        __builtin_amdgcn_s_barrier();
        const char* la = lds + (kt % 3) * BUFB;
        tile_compute(la, la + 32768, acc, rA, rB, g);
        __builtin_amdgcn_s_barrier();
    }
    asm volatile("s_waitcnt vmcnt(6)" ::: "memory");
    __builtin_amdgcn_s_barrier();
    {
        const char* la = lds + ((KT - 2) % 3) * BUFB;
        tile_compute(la, la + 32768, acc, rA, rB, g);
    }
    asm volatile("s_waitcnt vmcnt(0)" ::: "memory");
    __builtin_amdgcn_s_barrier();
    {
        const char* la = lds + ((KT - 1) % 3) * BUFB;
        tile_compute(la, la + 32768, acc, rA, rB, g);
    }

    // epilogue: + bias, exact gelu, * 32, store fp8 e4m3
    #pragma unroll
    for (int mi = 0; mi < 4; ++mi) {
        #pragma unroll
        for (int ni = 0; ni < 4; ++ni) {
            int col = n0 + wc * 64 + ni * 16 + rl;              // d
            float bg = bEmb[didx * D_ + col];
            #pragma unroll
            for (int r = 0; r < 4; ++r) {
                int row = m0 + wr * 64 + mi * 16 + g * 4 + r;   // t
                float v = acc[mi][ni][r] + bg;
                float gl = 0.5f * v * (1.0f + erff(v * 0.70710678118f)) * 32.0f;
                int pk = __builtin_amdgcn_cvt_pk_fp8_f32(gl, gl, 0, false);
                X18[((size_t)b * T_ + row) * D_ + col] = (unsigned char)pk;
            }
        }
    }
}

// ===== gemm2: MX-fp8 K128, 8 waves (2Mx4N), 2 blocks/CU ==================
// grid 512: xcd=id&7; slot=id>>3; b=xcd*4+(slot>>4); t=slot&15:
// m0=(t&1)*128, n0=(t>>1)*128. 48 K128-tiles, s-inner order.
__global__ __launch_bounds__(512, 4) void gemm2_proj(
    const unsigned char* __restrict__ X18,     // [B][T][D] fp8
    const unsigned char* __restrict__ Wp8,     // [H][KP] fp8 (x16 scaled)
    const float* __restrict__ bProj,
    const float* __restrict__ posTab,          // [MAXF][H] f32
    const int* __restrict__ tsIn,              // [B][T]
    float* __restrict__ outX) {                // [B][L][H]
    extern __shared__ __align__(16) char lds2[];   // 2 x 32KB [A 16K | B 16K]
    const int tid  = threadIdx.x;
    const int lane = tid & 63, wid = tid >> 6;     // 0..7
    const int wm = wid >> 2, wn = wid & 3;         // 2M x 4N
    const int id   = blockIdx.x;               // 0..511
    const int xcd  = id & 7, slot = id >> 3;   // 0..63
    const int b    = xcd * 4 + (slot >> 4);
    const int t    = slot & 15;
    const int m0   = (t & 1) * 128;            // l base
    const int n0   = (t >> 1) * 128;           // h base
    const unsigned char* Xb = X18 + (size_t)b * T_ * D_;
    const int KT = 48;                         // K128 tiles

    // staging: A tile [128 l-rows][128 fp8] 16KB + B tile 16KB per buffer.
    // 2048 chunks of 16B per buffer -> 4 gld_lds per thread (2 A + 2 B).
    const unsigned char* aP[2]; const unsigned char* bP[2]; int dstC[2];
    #pragma unroll
    for (int i = 0; i < 2; ++i) {
        int p = i * 512 + tid;          // 0..1023
        int row = p >> 3;               // 0..127
        int c = (p & 7) ^ (row & 7);
        int l = m0 + row; if (l > 254) l = 254;
        aP[i] = Xb + (size_t)(2 * l) * D_ + c * 16;
        bP[i] = Wp8 + (size_t)(n0 + row) * KP_ + c * 16;
        dstC[i] = (i * 512 + wid * 64) * 16;
    }
    auto stage = [&](int kt, int buf) {
        int ko = (kt & 3) * D_ + (kt >> 2) * 128;   // s-inner K order
        char* base = lds2 + buf * 32768;
        #pragma unroll
        for (int i = 0; i < 2; ++i) {
            gld_lds16(aP[i] + ko, base + dstC[i]);
            gld_lds16(bP[i] + ko, base + 16384 + dstC[i]);
        }
    };

    // fragment geometry: lane reads 32B of its row (chunks 2g, 2g+1 logical)
    const int rl = lane & 15, g = lane >> 4, sx = rl & 7;
    const int ck0 = ((2 * g) ^ sx) << 4;
    const int ck1 = ((2 * g + 1) ^ sx) << 4;
    int aOff[4], bOff[2];
    #pragma unroll
    for (int mi = 0; mi < 4; ++mi) aOff[mi] = (wm * 64 + mi * 16 + rl) * 128;
    #pragma unroll
    for (int ni = 0; ni < 2; ++ni) bOff[ni] = 16384 + (wn * 32 + ni * 16 + rl) * 128;

    union u8x32 { i32x8 v; i32x4 h[2]; };
    f32x4 acc[4][2] = {};

    stage(0, 0);
    for (int u = 0; u < KT; ++u) {
        int buf = u & 1;
        char* base = lds2 + buf * 32768;
        if (u + 1 < KT) {
            stage(u + 1, buf ^ 1);
            asm volatile("s_waitcnt vmcnt(4)" ::: "memory");
        } else {
            asm volatile("s_waitcnt vmcnt(0)" ::: "memory");
        }
        __builtin_amdgcn_s_barrier();

        u8x32 A[4], Bv[2];
        #pragma unroll
        for (int mi = 0; mi < 4; ++mi) {
            A[mi].h[0] = *(const i32x4*)(base + aOff[mi] + ck0);
            A[mi].h[1] = *(const i32x4*)(base + aOff[mi] + ck1);
        }
        #pragma unroll
        for (int ni = 0; ni < 2; ++ni) {
            Bv[ni].h[0] = *(const i32x4*)(base + bOff[ni] + ck0);
            Bv[ni].h[1] = *(const i32x4*)(base + bOff[ni] + ck1);
        }
        #pragma unroll
        for (int ni = 0; ni < 2; ++ni)
            #pragma unroll
            for (int mi = 0; mi < 4; ++mi)
                acc[mi][ni] = MFMA8(A[mi].v, Bv[ni].v, acc[mi][ni]);
        __builtin_amdgcn_s_barrier();    // all reads of buf done
    }

    // epilogue: + b_proj + pos_table[ts[l]], fp32 store
    #pragma unroll
    for (int mi = 0; mi < 4; ++mi) {
        #pragma unroll
        for (int ni = 0; ni < 2; ++ni) {
            int h = n0 + wn * 32 + ni * 16 + rl;
            float bp = bProj[h];
            #pragma unroll
            for (int r = 0; r < 4; ++r) {
                int l = m0 + wm * 64 + mi * 16 + g * 4 + r;
                if (l < L_) {
                    int tsv = tsIn[b * T_ + l];
                    float v = acc[mi][ni][r] + bp + posTab[(size_t)tsv * H_ + h];
                    outX[((size_t)b * L_ + l) * H_ + h] = v;
                }
            }
        }
    }
}

extern "C" void kernel_launch(void* const* d_in, const int* in_sizes, int n_in,
                              void* d_out, int out_size, void* d_ws, size_t ws_size,
                              hipStream_t stream) {
    (void)in_sizes; (void)n_in; (void)out_size; (void)ws_size;
    const float* spikes  = (const float*)d_in[0];
    const int*   smask   = (const int*)d_in[1];
    const int*   sts     = (const int*)d_in[2];
    const int*   dateIdx = (const int*)d_in[3];
    const float* Wemb    = (const float*)d_in[4];
    const float* bEmb    = (const float*)d_in[5];
    const float* Wproj   = (const float*)d_in[6];
    const float* bProj   = (const float*)d_in[7];
    const float* posTab  = (const float*)d_in[8];
    float* out = (float*)d_out;

    // workspace layout (bytes):
    // X18 fp8   [B][T][D]  : 25165824   @ 0
    // SpB bf16  [B][T][C]  : 12582912   @ 25165824
    // WeB bf16  [ND][D][C] : 18874368   @ 37748736
    // Wp8 fp8   [H][KP]    : 6291456    @ 56623104
    char* ws = (char*)d_ws;
    unsigned char*  X18 = (unsigned char*)(ws);
    __hip_bfloat16* SpB = (__hip_bfloat16*)(ws + 25165824);
    __hip_bfloat16* WeB = (__hip_bfloat16*)(ws + 37748736);
    unsigned char*  Wp8 = (unsigned char*)(ws + 56623104);

    hipFuncSetAttribute((const void*)gemm1_embed,
                        hipFuncAttributeMaxDynamicSharedMemorySize, 3 * BUFB);
    hipFuncSetAttribute((const void*)gemm2_proj,
                        hipFuncAttributeMaxDynamicSharedMemorySize, 65536);

    prep<<<21536, 256, 0, stream>>>(spikes, Wemb, Wproj, smask, sts,
                                    SpB, WeB, Wp8, out);

    gemm1_embed<<<768, 512, 3 * BUFB, stream>>>(SpB, WeB, bEmb, dateIdx, X18);

    gemm2_proj<<<512, 512, 65536, stream>>>(X18, Wp8, bProj, posTab, sts, out);
}